// Round 6
// baseline (199.915 us; speedup 1.0000x reference)
//
#include <hip/hip_runtime.h>
#include <math.h>

#define UNITS 64
#define TT 100
#define NB 16          // batch rows per tile = one MFMA M-tile
#define NTH 256        // 4 waves
#define HSTR 72        // hbuf row stride in halves (identity rows: b128 reads 2-way = free)
#define XQSTR 18       // xt quad stride per timestep (16 rows + 2 pad -> conflict-free)
#define RP 20          // zbuf row-dim pad (16 -> 20 f32): unit stride 80B = 16B-aligned, even bank spread

typedef _Float16 half8 __attribute__((ext_vector_type(8)));
typedef _Float16 half4 __attribute__((ext_vector_type(4)));
typedef float floatx4 __attribute__((ext_vector_type(4)));
typedef float floatx2 __attribute__((ext_vector_type(2)));

#define LOG2E 1.44269504088896f

__device__ __forceinline__ float rcp_fast(float x) { return __builtin_amdgcn_rcpf(x); }
__device__ __forceinline__ float exp2_fast(float x) { return __builtin_amdgcn_exp2f(x); }
__device__ __forceinline__ floatx2 fma2(floatx2 a, floatx2 b, floatx2 c) {
    return __builtin_elementwise_fma(a, b, c);
}

// Session ledger (key structural facts, do not re-derive):
//  - ONE dispatch; no cross-block sync; grid-level length sorting dead.
//  - r16 (8 waves) FAILED: VGPR cap spill -> 1.5 GB HBM. Layout needs ~91+ VGPR.
//  - r18 (NB=32, 2 waves/SIMD) FAILED: ILP does not substitute for TLP. 4 waves/SIMD optimum.
//  - r19 (packed f32 math): busy -12% (VALUBusy 65->57) but WALL FLAT at ~145us ->
//    kernel is latency/convoy-idle bound (43% idle) + trans stream (50% of wall).
//    Op-shaving on live cells is exhausted.
// Round 20 (this round): kill DEAD-ROW trans work (~31% of all cell-activations).
//  MFMA C-layout spreads rows across lanes -> per-row predication saves no issue.
//  Fix: LDS z-exchange. Phase 1: MFMA (roles unchanged), write z[4 gates][unit][rows]
//  to LDS. Barrier. Phase 2: row-major reassignment - wave w activates rows 4w..4w+3,
//  lane = unit. Rows rank-sorted by length (block-local) -> a wave's rows die
//  together -> wave-uniform skip of the whole activation (saves trans ISSUE).
//  Expected activation wave-steps: sum of quartile maxes ~268 vs 388 -> -30% trans.
//  Costs: +4 b128 writes, +4 b128 reads (RP=20: conflict-free), +1 barrier/step.
//  LDS ~39.7KB still 4 blocks/CU (epilogue h1buf/logitbuf overlay zbuf).
__global__ __launch_bounds__(NTH, 4) void lstm_kernel(
    const float* __restrict__ x,    // (B,100,3)
    const float* __restrict__ W,    // (3,256)
    const float* __restrict__ U,    // (64,256)
    const float* __restrict__ bias, // (256,)
    const float* __restrict__ W1,   // (64,64)
    const float* __restrict__ b1,   // (64,)
    const float* __restrict__ W2,   // (64,5)
    const float* __restrict__ b2,   // (5,)
    float* __restrict__ out, int B)
{
    __shared__ __align__(16) _Float16 hb[2][NB * HSTR];   // double-buffered h (f16)  4608 B
    __shared__ __align__(16) _Float16 xt[TT * XQSTR * 4]; // staged x quads          14400 B
    __shared__ __align__(16) float zsh[4 * 64 * RP];      // z exchange              20480 B
    __shared__ int llen_s[NB];                            // per-row lengths (orig order)
    __shared__ int perm_s[NB];                            // slot -> original row
    __shared__ int slen_s[NB];                            // slot lengths, descending

    float* const h1buf    = zsh;            // epilogue overlay (zbuf dead by then)
    float* const logitbuf = zsh + NB * 64;

    const int tid = threadIdx.x;
    const int w   = tid >> 6;
    const int l   = tid & 63;   // phase-2: unit index
    const int q   = l >> 4;
    const int cnl = l & 15;
    const int b0  = blockIdx.x * NB;
    const int grp = tid >> 4;   // slot/row within tile
    const int sub = tid & 15;   // lane within row

    // ---- per-row lengths (original order): 16 lanes/row, coalesced ----
    {
        const float* xp = x + (size_t)(b0 + grp) * (TT * 3);
        int m = 0;
        for (int t = sub; t < TT; t += 16) {
            const float a = xp[3*t], b = xp[3*t+1], c = xp[3*t+2];
            if (a != 0.0f || b != 0.0f || c != 0.0f) m = t + 1;
        }
        #pragma unroll
        for (int off = 8; off; off >>= 1) m = max(m, __shfl_down(m, off, 16));
        if (sub == 0) llen_s[grp] = m;
    }
    for (int i = tid; i < NB * HSTR; i += NTH) hb[0][i] = (_Float16)0.0f;
    __syncthreads();   // llen_s visible

    // ---- rank sort (descending length), branchless, no scratch ----
    if (tid < NB) {
        const int li = llen_s[tid];
        int rank = 0;
        #pragma unroll
        for (int j = 0; j < NB; ++j) {
            const int lj = llen_s[j];
            rank += (lj > li) || (lj == li && j < tid);
        }
        perm_s[rank] = tid;
        slen_s[rank] = li;
    }
    __syncthreads();   // perm/slen visible

    int maxlen = slen_s[0];
    int minlen = slen_s[NB - 1];
    maxlen = (maxlen < 0) ? 0 : ((maxlen > TT) ? TT : maxlen);
    minlen = (minlen < 0) ? 0 : ((minlen > maxlen) ? maxlen : minlen);
    int slr[4];
    #pragma unroll
    for (int r = 0; r < 4; ++r) slr[r] = slen_s[4*w + r];   // phase-2 rows of wave w
    const int GLw = slr[0];                                  // group max (sorted desc)

    // ---- stage x tile (PERMUTED slots) as f16 quads {x0,x1,x2,1} ----
    {
        const float* xp = x + (size_t)(b0 + perm_s[grp]) * (TT * 3);
        for (int t = sub; t < maxlen; t += 16) {
            const float a = xp[3*t], b = xp[3*t+1], c = xp[3*t+2];
            half4 v = { (_Float16)a, (_Float16)b, (_Float16)c, (_Float16)1.0f };
            *(half4*)&xt[(t * XQSTR + grp) * 4] = v;
        }
    }

    // ---- extended-K B fragments: rows 0..63=U, 64..66=W, 67=bias, 68..95=0.
    // PRESCALED: i,f,o by -LOG2E, g by -2*LOG2E.
    half8 Bf[4][3];
    {
        const float gscale[4] = { -LOG2E, -LOG2E, -2.0f * LOG2E, -LOG2E };
        #pragma unroll
        for (int g = 0; g < 4; ++g) {
            const int zc = 64 * g + 16 * w + cnl;
            #pragma unroll
            for (int kb = 0; kb < 3; ++kb)
                #pragma unroll
                for (int j = 0; j < 8; ++j) {
                    const int k = 32 * kb + 8 * q + j;
                    float v = 0.0f;
                    if (k < 64)       v = U[k * 256 + zc];
                    else if (k < 67)  v = W[(k - 64) * 256 + zc];
                    else if (k == 67) v = bias[zc];
                    Bf[g][kb][j] = (_Float16)(v * gscale[g]);
                }
        }
    }

    // cell state (scaled domain d = -2*LOG2E*c) for phase-2 rows {4w+0..3} x unit l
    floatx2 d01 = {0.0f, 0.0f}, d23 = {0.0f, 0.0f};
    _Float16 hcur[4] = {(_Float16)0.0f, (_Float16)0.0f, (_Float16)0.0f, (_Float16)0.0f};
    const floatx4 zero4 = {0.0f, 0.0f, 0.0f, 0.0f};
    const floatx2 one2  = {1.0f, 1.0f};
    const floatx2 c2L   = {2.0f*LOG2E, 2.0f*LOG2E};
    const floatx2 cm2L  = {-2.0f*LOG2E, -2.0f*LOG2E};
    const floatx2 clamp2 = {80.0f, 80.0f};

    const int rsl = cnl * HSTR;                          // phase-1 A-read base
    const int zwr = (16*w + cnl) * RP + 4*q;             // phase-1 z-write base (+ g*64*RP)
    const int zrd = l * RP + 4*w;                        // phase-2 z-read  base (+ g*64*RP)
    const int hwr = (4*w) * HSTR + l;                    // phase-2 h-write base (+ r*HSTR)

    __syncthreads();   // staging + hb[0] zero visible

// phase-2 activation on a row pair {R0, R0+1}; zr[g] = floatx4 over the 4 rows
#define ACT_PAIR(R0, DST)                                                     \
    {                                                                         \
        const floatx2 ei2 = { exp2_fast(zr[0][R0]), exp2_fast(zr[0][R0+1]) }; \
        const floatx2 ef2 = { exp2_fast(zr[1][R0]), exp2_fast(zr[1][R0+1]) }; \
        const floatx2 eg2 = { exp2_fast(zr[2][R0]), exp2_fast(zr[2][R0+1]) }; \
        const floatx2 eo2 = { exp2_fast(zr[3][R0]), exp2_fast(zr[3][R0+1]) }; \
        const floatx2 Ag2 = one2 + eg2;                                       \
        const floatx2 P2  = fma2(ei2, Ag2, Ag2);          /* (1+ei)(1+eg) */  \
        const floatx2 Af2 = one2 + ef2;                                       \
        const floatx2 R2  = P2 * Af2;                                         \
        const floatx2 tg2 = fma2(c2L, eg2, cm2L);         /* -2L(1-eg)   */   \
        const floatx2 nm2 = fma2(DST, P2, tg2 * Af2);                         \
        const floatx2 rR2 = { rcp_fast(R2[0]), rcp_fast(R2[1]) };             \
        const floatx2 dn2 = nm2 * rR2;                                        \
        DST = dn2;                                                            \
        const floatx2 dc2 = __builtin_elementwise_min(dn2, clamp2);           \
        const floatx2 ed2 = { exp2_fast(dc2[0]), exp2_fast(dc2[1]) };         \
        const floatx2 D22 = one2 + ed2;                                       \
        const floatx2 Q2  = fma2(eo2, D22, D22);          /* (1+eo)(1+ed) */  \
        const floatx2 s2  = one2 - ed2;                                       \
        const floatx2 rQ2 = { rcp_fast(Q2[0]), rcp_fast(Q2[1]) };             \
        const floatx2 hv2 = s2 * rQ2;                                         \
        hcur[R0]   = (_Float16)hv2[0];                                        \
        hcur[R0+1] = (_Float16)hv2[1];                                        \
    }

#define ACT_PAIR_MASK(R0, DST)                                                \
    {                                                                         \
        const bool lv0 = (t < slr[R0]), lv1 = (t < slr[R0+1]);                \
        const floatx2 ei2 = { exp2_fast(zr[0][R0]), exp2_fast(zr[0][R0+1]) }; \
        const floatx2 ef2 = { exp2_fast(zr[1][R0]), exp2_fast(zr[1][R0+1]) }; \
        const floatx2 eg2 = { exp2_fast(zr[2][R0]), exp2_fast(zr[2][R0+1]) }; \
        const floatx2 eo2 = { exp2_fast(zr[3][R0]), exp2_fast(zr[3][R0+1]) }; \
        const floatx2 Ag2 = one2 + eg2;                                       \
        const floatx2 P2  = fma2(ei2, Ag2, Ag2);                              \
        const floatx2 Af2 = one2 + ef2;                                       \
        const floatx2 R2  = P2 * Af2;                                         \
        const floatx2 tg2 = fma2(c2L, eg2, cm2L);                             \
        const floatx2 nm2 = fma2(DST, P2, tg2 * Af2);                         \
        const floatx2 rR2 = { rcp_fast(R2[0]), rcp_fast(R2[1]) };             \
        const floatx2 dn2 = nm2 * rR2;                                        \
        DST[0] = lv0 ? dn2[0] : DST[0];                                       \
        DST[1] = lv1 ? dn2[1] : DST[1];                                       \
        const floatx2 dc2 = __builtin_elementwise_min(dn2, clamp2);           \
        const floatx2 ed2 = { exp2_fast(dc2[0]), exp2_fast(dc2[1]) };         \
        const floatx2 D22 = one2 + ed2;                                       \
        const floatx2 Q2  = fma2(eo2, D22, D22);                              \
        const floatx2 s2  = one2 - ed2;                                       \
        const floatx2 rQ2 = { rcp_fast(Q2[0]), rcp_fast(Q2[1]) };             \
        const floatx2 hv2 = s2 * rQ2;                                         \
        hcur[R0]   = lv0 ? (_Float16)hv2[0] : hcur[R0];                       \
        hcur[R0+1] = lv1 ? (_Float16)hv2[1] : hcur[R0+1];                     \
    }

// phase 1: MFMA z = [h|x|1] @ [U;W;b] (prescaled), write z to zsh
#define PHASE1                                                                 \
    {                                                                          \
        const half8 A0 = *(const half8*)&hbc[rsl + 8 * q];                     \
        const half8 A1 = *(const half8*)&hbc[rsl + 32 + 8 * q];                \
        const half4 x4 = *(const half4*)&xt[(t * XQSTR + cnl) * 4];            \
        const half8 AX = { x4[0], x4[1], x4[2], x4[3],                         \
                           (_Float16)0.0f, (_Float16)0.0f, (_Float16)0.0f, (_Float16)0.0f }; \
        floatx4 acc[4];                                                        \
        _Pragma("unroll")                                                      \
        for (int g = 0; g < 4; ++g) {                                          \
            acc[g] = __builtin_amdgcn_mfma_f32_16x16x32_f16(AX, Bf[g][2], zero4, 0, 0, 0); \
            acc[g] = __builtin_amdgcn_mfma_f32_16x16x32_f16(A0, Bf[g][0], acc[g], 0, 0, 0); \
            acc[g] = __builtin_amdgcn_mfma_f32_16x16x32_f16(A1, Bf[g][1], acc[g], 0, 0, 0); \
        }                                                                      \
        _Pragma("unroll")                                                      \
        for (int g = 0; g < 4; ++g)                                            \
            *(floatx4*)&zsh[g * 64 * RP + zwr] = acc[g];                       \
    }

    int t = 0;

    // ---- unmasked main loop: all 16 rows live for t < minlen ----
    #pragma unroll 1
    for (; t < minlen; ++t) {
        const _Float16* hbc = hb[t & 1];
        _Float16*       hbn = hb[(t + 1) & 1];
        PHASE1
        __syncthreads();   // z visible
        {
            floatx4 zr[4];
            #pragma unroll
            for (int g = 0; g < 4; ++g)
                zr[g] = *(const floatx4*)&zsh[g * 64 * RP + zrd];
            ACT_PAIR(0, d01)
            ACT_PAIR(2, d23)
        }
        hbn[hwr]            = hcur[0];
        hbn[hwr + HSTR]     = hcur[1];
        hbn[hwr + 2*HSTR]   = hcur[2];
        hbn[hwr + 3*HSTR]   = hcur[3];
        __syncthreads();   // h visible
    }

    // ---- masked tail: wave-uniform skip once this wave's row group is dead ----
    #pragma unroll 1
    for (; t < maxlen; ++t) {
        const _Float16* hbc = hb[t & 1];
        _Float16*       hbn = hb[(t + 1) & 1];
        PHASE1
        __syncthreads();   // z visible
        if (t < GLw) {     // wave-uniform: saves the whole trans stream when dead
            floatx4 zr[4];
            #pragma unroll
            for (int g = 0; g < 4; ++g)
                zr[g] = *(const floatx4*)&zsh[g * 64 * RP + zrd];
            ACT_PAIR_MASK(0, d01)
            ACT_PAIR_MASK(2, d23)
        }
        hbn[hwr]            = hcur[0];   // always: keep both buffers fresh
        hbn[hwr + HSTR]     = hcur[1];
        hbn[hwr + 2*HSTR]   = hcur[2];
        hbn[hwr + 3*HSTR]   = hcur[3];
        __syncthreads();   // h visible
    }

    const _Float16* hbL = hb[maxlen & 1];

    // ---- epilogue: h1 = relu(h @ W1 + b1)  (h1buf overlays zsh; zbuf dead) ----
    {
        const int j  = tid & 63;
        const int bb = tid >> 6;
        const float bj = b1[j];
        #pragma unroll
        for (int p = 0; p < NB / 4; ++p) {
            const int b = p * 4 + bb;
            float acc = bj;
            #pragma unroll 8
            for (int k = 0; k < UNITS; ++k)
                acc += (float)hbL[b * HSTR + k] * W1[k * 64 + j];
            h1buf[b * 64 + j] = fmaxf(acc, 0.0f);
        }
    }
    __syncthreads();

    if (tid < NB * 5) {
        const int b = tid / 5, s = tid % 5;
        float acc = b2[s];
        for (int j = 0; j < 64; ++j)
            acc += h1buf[b * 64 + j] * W2[j * 5 + s];
        logitbuf[b * 5 + s] = acc;
    }
    __syncthreads();

    if (tid < NB) {
        const int gb = b0 + perm_s[tid];   // un-permute slots -> batch rows
        const float l0 = logitbuf[tid * 5 + 0];
        const float l1 = logitbuf[tid * 5 + 1];
        const float l2 = logitbuf[tid * 5 + 2];
        const float l3 = logitbuf[tid * 5 + 3];
        const float l4 = logitbuf[tid * 5 + 4];
        const float m  = fmaxf(fmaxf(fmaxf(l0, l1), fmaxf(l2, l3)), l4);
        const float e0 = __expf(l0 - m), e1 = __expf(l1 - m), e2 = __expf(l2 - m);
        const float e3 = __expf(l3 - m), e4 = __expf(l4 - m);
        const float rs = 1.0f / (e0 + e1 + e2 + e3 + e4);
        out[(size_t)gb * 5 + 0] = e0 * rs;
        out[(size_t)gb * 5 + 1] = e1 * rs;
        out[(size_t)gb * 5 + 2] = e2 * rs;
        out[(size_t)gb * 5 + 3] = e3 * rs;
        out[(size_t)gb * 5 + 4] = e4 * rs;
    }
#undef ACT_PAIR
#undef ACT_PAIR_MASK
#undef PHASE1
}

extern "C" void kernel_launch(void* const* d_in, const int* in_sizes, int n_in,
                              void* d_out, int out_size, void* d_ws, size_t ws_size,
                              hipStream_t stream) {
    const float* x  = (const float*)d_in[0];
    const float* W  = (const float*)d_in[1];
    const float* U  = (const float*)d_in[2];
    const float* b  = (const float*)d_in[3];
    const float* W1 = (const float*)d_in[4];
    const float* b1 = (const float*)d_in[5];
    const float* W2 = (const float*)d_in[6];
    const float* b2 = (const float*)d_in[7];
    float* out = (float*)d_out;

    const int B = in_sizes[0] / (TT * 3);   // 16384

    lstm_kernel<<<dim3(B / NB), dim3(NTH), 0, stream>>>(
        x, W, U, b, W1, b1, W2, b2, out, B);
}